// Round 2
// baseline (901.680 us; speedup 1.0000x reference)
//
#include <hip/hip_runtime.h>
#include <hip/hip_fp16.h>

typedef short v8s __attribute__((ext_vector_type(8)));
typedef short v4s __attribute__((ext_vector_type(4)));
typedef float v4f __attribute__((ext_vector_type(4)));

#define BM 128
#define BN 128
#define BK 64

__device__ __forceinline__ float b2f(unsigned short u) {
    union { unsigned int i; float f; } x; x.i = ((unsigned int)u) << 16; return x.f;
}
__device__ __forceinline__ unsigned short f2b(float f) {
    union { float f; unsigned int i; } x; x.f = f;
    unsigned int r = x.i + 0x7fffu + ((x.i >> 16) & 1u);
    return (unsigned short)(r >> 16);
}
__device__ __forceinline__ unsigned short f2h(float f) {
    return __half_as_ushort(__float2half(f));
}
__device__ __forceinline__ float h2f(unsigned short u) {
    return __half2float(__ushort_as_half(u));
}

// async global->LDS, 16B per lane. LDS dest is wave-uniform base + lane*16,
// so LDS layout is linear; swizzle is applied on the GLOBAL source address.
__device__ __forceinline__ void gload16(const void* g, void* l) {
    __builtin_amdgcn_global_load_lds(
        (const __attribute__((address_space(1))) void*)g,
        (__attribute__((address_space(3))) void*)l, 16, 0, 0);
}

// Generic MFMA GEMM: C[m,n] = sum_k A[m,k] * BT[n,k]  (+ epilogue). All bf16.
// LDS tiles linear [128][64] (row = 8 chunks of 16B); chunk swizzle c^=(row&7)
// on both the staging source and the ds_read side (involution).
// EPI: 0 plain bf16 store
//      1 transposed bf16 store (batch from gm, 512 rows/batch)
//      2 +bias_f32[gm], bf16 store | 4 +resid_f32[gm*ldr+gn], bf16 store
template<int EPI>
__global__ __launch_bounds__(256)
void gemm_bt(const unsigned short* __restrict__ A, int lda, long aSB,
             const unsigned short* __restrict__ BT, int ldb, long bSB,
             void* __restrict__ C, int ldc, long cSB,
             int K,
             const float* __restrict__ bias,
             const float* __restrict__ resid, int ldr)
{
    const int z = blockIdx.z;

    __shared__ unsigned short As[BM * BK];   // 16 KB
    __shared__ unsigned short Bs[BN * BK];   // 16 KB

    const int tid = threadIdx.x;
    const int wave = tid >> 6, lane = tid & 63;
    const int wm = (wave >> 1) * 64, wn = (wave & 1) * 64;
    const int quad = lane >> 4, l16 = lane & 15;
    const int sx = l16 & 7;
    const int bm = blockIdx.y * BM, bn = blockIdx.x * BN;

    // k0-invariant staging addresses (row, swizzled chunk per thread)
    const unsigned short* aP[4]; const unsigned short* bP[4];
    unsigned short* lA[4]; unsigned short* lB[4];
#pragma unroll
    for (int p = 0; p < 4; p++) {
        int idx = p * 256 + tid;
        int row = idx >> 3, c = idx & 7, cc = c ^ (row & 7);
        aP[p] = A + (long)z * aSB + (long)(bm + row) * lda + cc * 8;
        bP[p] = BT + (long)z * bSB + (long)(bn + row) * ldb + cc * 8;
        lA[p] = &As[idx * 8];
        lB[p] = &Bs[idx * 8];
    }

    v4f acc[4][4] = {};

    for (int k0 = 0; k0 < K; k0 += BK) {
#pragma unroll
        for (int p = 0; p < 4; p++) {
            gload16(aP[p] + k0, lA[p]);
            gload16(bP[p] + k0, lB[p]);
        }
        __syncthreads();   // drains vmcnt for the global_load_lds queue
#pragma unroll
        for (int ks = 0; ks < 2; ks++) {
            v8s af[4], bf[4];
#pragma unroll
            for (int i = 0; i < 4; i++) {
                const int co = ((ks * 4 + quad) ^ sx) * 8;
                af[i] = *(const v8s*)&As[(wm + i * 16 + l16) * 64 + co];
                bf[i] = *(const v8s*)&Bs[(wn + i * 16 + l16) * 64 + co];
            }
#pragma unroll
            for (int i = 0; i < 4; i++)
#pragma unroll
                for (int j = 0; j < 4; j++)
                    acc[i][j] = __builtin_amdgcn_mfma_f32_16x16x32_bf16(af[i], bf[j], acc[i][j], 0, 0, 0);
        }
        __syncthreads();
    }

    unsigned short* Cu = (unsigned short*)C + (long)z * cSB;

#pragma unroll
    for (int i = 0; i < 4; i++) {
        int rowbase = wm + i * 16 + quad * 4;
#pragma unroll
        for (int j = 0; j < 4; j++) {
            int gn = bn + wn + j * 16 + l16;
#pragma unroll
            for (int r = 0; r < 4; r++) {
                int gm = bm + rowbase + r;
                float v = acc[i][j][r];
                if (EPI == 0) {
                    Cu[(long)gm * ldc + gn] = f2b(v);
                } else if (EPI == 1) {
                    int bb = gm >> 9, mm = gm & 511;
                    ((unsigned short*)C)[(long)bb * cSB + (long)gn * ldc + mm] = f2b(v);
                } else if (EPI == 2) {
                    Cu[(long)gm * ldc + gn] = f2b(v + bias[gm]);
                } else if (EPI == 4) {
                    Cu[(long)gm * ldc + gn] = f2b(v + resid[(long)gm * ldr + gn]);
                }
            }
        }
    }
}

// Fused scores + mask + softmax + attn-write + PV.
// One block = 4 waves x 16 q-rows = 64 q-rows for one (b,h); all 512 kcols.
// Swapped QK^T: mfma(K,Q) -> lane holds one q-row x 128 kcols. Scores kept
// packed f16 in 64 u32 regs (halves reg footprint -> 3 waves/SIMD). P round-
// trips through wave-PRIVATE 8KB LDS in two 256-col halves (XOR-swizzled,
// conflict-free); K and V fragments stream from global (L2-hot). No barriers.
__global__ __launch_bounds__(256, 3)
void scores_pv_k(const unsigned short* __restrict__ q1c,
                 const unsigned short* __restrict__ k1c,
                 const unsigned short* __restrict__ v1t,
                 float* __restrict__ attn,
                 unsigned short* __restrict__ out1,
                 const int* __restrict__ mask1,
                 const int* __restrict__ mask2,
                 float scale)
{
    // XCD-aware swizzle of flat grid 2048 = 256 (b,h) x 8 row-chunks:
    // put the 8 chunks sharing one (b,h)'s K/V slabs on the same XCD.
    const int id = blockIdx.x;
    const int logical = (id & 7) * 256 + (id >> 3);
    const int z = logical >> 3;
    const int bx = logical & 7;
    const int b = z >> 3, h = z & 7;

    const unsigned short* Qb = q1c + (long)b * 262144 + h * 64;   // (512 seq, 512 feat)
    const unsigned short* Kb = k1c + (long)b * 262144 + h * 64;
    const unsigned short* Vb = v1t + (long)b * 524288 + (long)h * 65536;  // (128 dv, 512 seq)

    const int tid = threadIdx.x;
    const int wave = tid >> 6, lane = tid & 63;
    const int quad = lane >> 4, l16 = lane & 15;
    const int swz = l16 & 7;
    const int bm = bx * 64;
    const int row_l = wave * 16 + l16;
    const int qrow = bm + row_l;

    __shared__ unsigned short Pl[4][4096];   // 8 KB per wave: [16 rows][256B-swizzled cols]

    v8s qf0 = *(const v8s*)&Qb[(long)qrow * 512 + quad * 8];
    v8s qf1 = *(const v8s*)&Qb[(long)qrow * 512 + 32 + quad * 8];

    const int m1 = mask1[b * 512 + qrow];
    const int* m2p = mask2 + b * 512;
    const unsigned short* Krow = Kb + (long)l16 * 512 + quad * 8;

    unsigned int u[64];
    float mx = -1e30f;

    // pass 1: QK^T, scale+mask, pack scores to f16, track row max
#pragma unroll
    for (int jg = 0; jg < 8; jg++) {
        v8s kf0[4], kf1[4];
#pragma unroll
        for (int t = 0; t < 4; t++) {
            long off = (long)(jg * 4 + t) * 8192;
            kf0[t] = *(const v8s*)&Krow[off];
            kf1[t] = *(const v8s*)&Krow[off + 32];
        }
#pragma unroll
        for (int t = 0; t < 4; t++) {
            int j = jg * 4 + t;
            v4f a = (v4f){0.f, 0.f, 0.f, 0.f};
            a = __builtin_amdgcn_mfma_f32_16x16x32_bf16(kf0[t], qf0, a, 0, 0, 0);
            a = __builtin_amdgcn_mfma_f32_16x16x32_bf16(kf1[t], qf1, a, 0, 0, 0);
            int4 m2v = *(const int4*)&m2p[j * 16 + quad * 4];
            float s0 = (m1 != 0 || m2v.x != 0) ? 1e-9f : a[0] * scale;
            float s1 = (m1 != 0 || m2v.y != 0) ? 1e-9f : a[1] * scale;
            float s2 = (m1 != 0 || m2v.z != 0) ? 1e-9f : a[2] * scale;
            float s3 = (m1 != 0 || m2v.w != 0) ? 1e-9f : a[3] * scale;
            mx = fmaxf(mx, fmaxf(fmaxf(s0, s1), fmaxf(s2, s3)));
            u[2 * j]     = (unsigned int)f2h(s0) | ((unsigned int)f2h(s1) << 16);
            u[2 * j + 1] = (unsigned int)f2h(s2) | ((unsigned int)f2h(s3) << 16);
        }
    }
    mx = fmaxf(mx, __shfl_xor(mx, 16, 64));
    mx = fmaxf(mx, __shfl_xor(mx, 32, 64));

    // pass 2: exp + row sum (overwrite u with packed-f16 e)
    float sum = 0.f;
#pragma unroll
    for (int j = 0; j < 32; j++) {
        float s0 = h2f((unsigned short)(u[2 * j] & 0xffffu));
        float s1 = h2f((unsigned short)(u[2 * j] >> 16));
        float s2 = h2f((unsigned short)(u[2 * j + 1] & 0xffffu));
        float s3 = h2f((unsigned short)(u[2 * j + 1] >> 16));
        float e0 = __expf(s0 - mx), e1 = __expf(s1 - mx);
        float e2 = __expf(s2 - mx), e3 = __expf(s3 - mx);
        sum += (e0 + e1) + (e2 + e3);
        u[2 * j]     = (unsigned int)f2h(e0) | ((unsigned int)f2h(e1) << 16);
        u[2 * j + 1] = (unsigned int)f2h(e2) | ((unsigned int)f2h(e3) << 16);
    }
    sum += __shfl_xor(sum, 16, 64);
    sum += __shfl_xor(sum, 32, 64);
    const float inv = 1.0f / sum;

    // pass 3 (per 256-col half): write attn f32 + P bf16 -> wave-private LDS,
    // then PV MFMAs for that half. Wave-private => no barriers.
    float* Arow = attn + (long)z * 262144 + (long)qrow * 512;
    char* Pw = (char*)&Pl[wave][0] + l16 * 512;
    v4f acc2[8];
#pragma unroll
    for (int t = 0; t < 8; t++) acc2[t] = (v4f){0.f, 0.f, 0.f, 0.f};

#pragma unroll
    for (int half = 0; half < 2; half++) {
#pragma unroll
        for (int jp = 0; jp < 16; jp++) {
            int j = half * 16 + jp;
            float p0 = h2f((unsigned short)(u[2 * j] & 0xffffu)) * inv;
            float p1 = h2f((unsigned short)(u[2 * j] >> 16)) * inv;
            float p2 = h2f((unsigned short)(u[2 * j + 1] & 0xffffu)) * inv;
            float p3 = h2f((unsigned short)(u[2 * j + 1] >> 16)) * inv;
            float4 w4; w4.x = p0; w4.y = p1; w4.z = p2; w4.w = p3;
            *(float4*)&Arow[j * 16 + quad * 4] = w4;
            unsigned int lo = (unsigned int)f2b(p0) | ((unsigned int)f2b(p1) << 16);
            unsigned int hi = (unsigned int)f2b(p2) | ((unsigned int)f2b(p3) << 16);
            int slot = 2 * jp + (quad >> 1);
            uint2 pr; pr.x = lo; pr.y = hi;
            *(uint2*)(Pw + (((slot ^ swz) << 4) | ((quad & 1) << 3))) = pr;
        }
        const unsigned short* Vh = Vb + half * 256;
#pragma unroll
        for (int c = 0; c < 8; c++) {
            v8s pf = *(const v8s*)(Pw + (((c * 4 + quad) ^ swz) << 4));
            v8s vf[8];
#pragma unroll
            for (int t = 0; t < 8; t++)
                vf[t] = *(const v8s*)&Vh[(long)(t * 16 + l16) * 512 + c * 32 + quad * 8];
#pragma unroll
            for (int t = 0; t < 8; t++)
                acc2[t] = __builtin_amdgcn_mfma_f32_16x16x32_bf16(vf[t], pf, acc2[t], 0, 0, 0);
        }
    }

    // out1[b][qrow][h*128 + dv], dv = t*16 + quad*4 + r
    unsigned short* Orow = out1 + (long)b * 524288 + (long)qrow * 1024 + h * 128;
#pragma unroll
    for (int t = 0; t < 8; t++) {
        v4s o;
        o[0] = (short)f2b(acc2[t][0]); o[1] = (short)f2b(acc2[t][1]);
        o[2] = (short)f2b(acc2[t][2]); o[3] = (short)f2b(acc2[t][3]);
        *(v4s*)&Orow[t * 16 + quad * 4] = o;
    }
}

// all prep: 4 weight transposes (f32 -> bf16^T) + Wconv cast + v linear cast
// + per-batch q/k transposed casts (for the seq-mix GEMM's BT operand)
__global__ __launch_bounds__(256)
void prep_k(const float* __restrict__ Wq, const float* __restrict__ Wk,
            const float* __restrict__ Wv, const float* __restrict__ Wfc,
            const float* __restrict__ Wconv,
            const float* __restrict__ qf, const float* __restrict__ kf,
            const float* __restrict__ vf,
            unsigned short* __restrict__ WqT, unsigned short* __restrict__ WkT,
            unsigned short* __restrict__ WvT, unsigned short* __restrict__ WfcT,
            unsigned short* __restrict__ Wconv_b,
            unsigned short* __restrict__ qT, unsigned short* __restrict__ kT,
            unsigned short* __restrict__ vb)
{
    __shared__ float t[32][33];
    int blk = blockIdx.x, tid = threadIdx.x;
    if (blk < 2304) {
        const float* src; unsigned short* dst; int K, N, local;
        if (blk < 384)       { src = Wq;  dst = WqT;  K = 768;  N = 512;  local = blk; }
        else if (blk < 768)  { src = Wk;  dst = WkT;  K = 768;  N = 512;  local = blk - 384; }
        else if (blk < 1536) { src = Wv;  dst = WvT;  K = 768;  N = 1024; local = blk - 768; }
        else                 { src = Wfc; dst = WfcT; K = 1024; N = 768;  local = blk - 1536; }
        int nb32 = N >> 5;
        int kb32 = (local / nb32) * 32, nb = (local % nb32) * 32;
        int tx = tid & 31, ty = tid >> 5;
#pragma unroll
        for (int i = 0; i < 32; i += 8)
            t[ty + i][tx] = src[(long)(kb32 + ty + i) * N + nb + tx];
        __syncthreads();
#pragma unroll
        for (int i = 0; i < 32; i += 8)
            dst[(long)(nb + ty + i) * K + kb32 + tx] = f2b(t[tx][ty + i]);
    } else if (blk < 3328) {
        int i = (blk - 2304) * 256 + tid;   // Wconv: 512*512 = 262144
        Wconv_b[i] = f2b(Wconv[i]);
    } else if (blk < 6400) {
        long i = (long)(blk - 3328) * 4096 + (long)tid * 16;   // v cast, 16 elems/thread
        float4 a = *(const float4*)&vf[i];
        float4 b4 = *(const float4*)&vf[i + 4];
        float4 c4 = *(const float4*)&vf[i + 8];
        float4 d4 = *(const float4*)&vf[i + 12];
        v8s r0, r1;
        r0[0] = (short)f2b(a.x);  r0[1] = (short)f2b(a.y);
        r0[2] = (short)f2b(a.z);  r0[3] = (short)f2b(a.w);
        r0[4] = (short)f2b(b4.x); r0[5] = (short)f2b(b4.y);
        r0[6] = (short)f2b(b4.z); r0[7] = (short)f2b(b4.w);
        r1[0] = (short)f2b(c4.x); r1[1] = (short)f2b(c4.y);
        r1[2] = (short)f2b(c4.z); r1[3] = (short)f2b(c4.w);
        r1[4] = (short)f2b(d4.x); r1[5] = (short)f2b(d4.y);
        r1[6] = (short)f2b(d4.z); r1[7] = (short)f2b(d4.w);
        *(v8s*)&vb[i] = r0;
        *(v8s*)&vb[i + 8] = r1;
    } else {
        int local = blk - 6400;                     // 24576 tile-transposes
        const float* src = (local < 12288) ? qf : kf;
        unsigned short* dst = (local < 12288) ? qT : kT;
        int li = (local < 12288) ? local : local - 12288;
        int bt = li / 384, tt = li % 384;
        int r32 = (tt / 24) * 32, c32 = (tt % 24) * 32;
        const float* S = src + (long)bt * 393216;
        unsigned short* D = dst + (long)bt * 393216;
        int tx = tid & 31, ty = tid >> 5;
#pragma unroll
        for (int i = 0; i < 32; i += 8)
            t[ty + i][tx] = S[(long)(r32 + ty + i) * 768 + c32 + tx];
        __syncthreads();
#pragma unroll
        for (int i = 0; i < 32; i += 8)
            D[(long)(c32 + ty + i) * 512 + r32 + tx] = f2b(t[tx][ty + i]);
    }
}

// LayerNorm over rows of 768 (bf16 in, f32 gamma/beta, f32 out) + nan->0
__global__ __launch_bounds__(256)
void ln_k(const unsigned short* __restrict__ x,
          const float* __restrict__ gamma,
          const float* __restrict__ beta,
          float* __restrict__ out)
{
    long row = (long)blockIdx.x * 4 + (threadIdx.x >> 6);
    int lane = threadIdx.x & 63;
    const unsigned short* p = x + row * 768;
    v8s a = *(const v8s*)&p[lane * 8];          // cols lane*8 .. +7
    v4s b4 = *(const v4s*)&p[512 + lane * 4];   // cols 512+lane*4 .. +3
    float v[12];
    float s = 0.f, s2 = 0.f;
#pragma unroll
    for (int j = 0; j < 8; j++) { v[j] = b2f((unsigned short)a[j]); s += v[j]; s2 += v[j] * v[j]; }
#pragma unroll
    for (int j = 0; j < 4; j++) { v[8 + j] = b2f((unsigned short)b4[j]); s += v[8 + j]; s2 += v[8 + j] * v[8 + j]; }
#pragma unroll
    for (int o = 32; o > 0; o >>= 1) { s += __shfl_xor(s, o, 64); s2 += __shfl_xor(s2, o, 64); }
    float mean = s * (1.0f / 768.0f);
    float var = s2 * (1.0f / 768.0f) - mean * mean;
    if (!(var >= 0.f)) var = 0.f;
    float rstd = rsqrtf(var + 1e-6f);
    float o12[12];
#pragma unroll
    for (int j = 0; j < 8; j++) {
        int c = lane * 8 + j;
        float o = (v[j] - mean) * rstd * gamma[c] + beta[c];
        union { float f; unsigned int i; } uu; uu.f = o;
        if ((uu.i & 0x7FFFFFFFu) > 0x7F800000u) uu.f = 0.f;
        o12[j] = uu.f;
    }
#pragma unroll
    for (int j = 0; j < 4; j++) {
        int c = 512 + lane * 4 + j;
        float o = (v[8 + j] - mean) * rstd * gamma[c] + beta[c];
        union { float f; unsigned int i; } uu; uu.f = o;
        if ((uu.i & 0x7FFFFFFFu) > 0x7F800000u) uu.f = 0.f;
        o12[8 + j] = uu.f;
    }
    float4 f0; f0.x = o12[0]; f0.y = o12[1]; f0.z = o12[2]; f0.w = o12[3];
    float4 f1; f1.x = o12[4]; f1.y = o12[5]; f1.z = o12[6]; f1.w = o12[7];
    float4 f2; f2.x = o12[8]; f2.y = o12[9]; f2.z = o12[10]; f2.w = o12[11];
    *(float4*)&out[row * 768 + lane * 8] = f0;
    *(float4*)&out[row * 768 + lane * 8 + 4] = f1;
    *(float4*)&out[row * 768 + 512 + lane * 4] = f2;
}

extern "C" void kernel_launch(void* const* d_in, const int* in_sizes, int n_in,
                              void* d_out, int out_size, void* d_ws, size_t ws_size,
                              hipStream_t stream)
{
    // B=32, L=512, D_EMB=768, D_K=512, D_V=1024, H=8 — all I/O float32
    const float* q     = (const float*)d_in[0];
    const float* k     = (const float*)d_in[1];
    const float* v     = (const float*)d_in[2];
    const float* Wq    = (const float*)d_in[3];
    const float* Wk    = (const float*)d_in[4];
    const float* Wv    = (const float*)d_in[5];
    const float* Wconv = (const float*)d_in[6];
    const float* bconv = (const float*)d_in[7];
    const float* Wfc   = (const float*)d_in[8];
    const float* gamma = (const float*)d_in[9];
    const float* beta  = (const float*)d_in[10];
    const int* mask1   = (const int*)d_in[11];
    const int* mask2   = (const int*)d_in[12];

    float* out  = (float*)d_out;               // (32,512,768) f32
    float* attn = out + 12582912;              // (32,8,512,512) f32

    // ws layout (ushort elems)
    unsigned short* ws = (unsigned short*)d_ws;
    unsigned short* WqT     = ws;              // 512x768
    unsigned short* WkT     = ws + 393216;     // 512x768
    unsigned short* WvT     = ws + 786432;     // 1024x768
    unsigned short* WfcT    = ws + 1572864;    // 768x1024
    unsigned short* Wconv_b = ws + 2359296;    // 512x512
    unsigned short* q1c     = ws + 2621440;    // (32,512,512)
    unsigned short* k1c     = ws + 11010048;   // (32,512,512)
    unsigned short* v1t     = ws + 19398656;   // (32,1024,512)  [.. 36175872)
    unsigned short* out2    = ws + 19398656;   // (32,512,768)  aliases v1t (dead after scores_pv)

    // scratch in d_out's attn region (268 MB) — all dead before scores_pv writes attn
    unsigned short* aScr = (unsigned short*)attn;
    unsigned short* qT = aScr;                 // (32,768,512) bf16 q^T per batch
    unsigned short* kT = aScr + 12582912;      // (32,768,512)
    unsigned short* Sq = aScr + 25165824;      // (32,512,768) seq-mixed q
    unsigned short* Sk = aScr + 37748736;      // (32,512,768)
    unsigned short* vb = aScr + 50331648;      // (32,512,768) bf16 cast of v [..62914560)
    // out1 in d_out's "out" region; consumed by FC before ln_k overwrites it.
    unsigned short* out1 = (unsigned short*)out;   // (32,512,1024) bf16

    prep_k<<<30976, 256, 0, stream>>>(Wq, Wk, Wv, Wfc, Wconv, q, k, v,
                                      WqT, WkT, WvT, WfcT, Wconv_b, qT, kT, vb);

    const float scale = 0.04419417382415922f;  // 1/sqrt(512)

    // seq-mix first (conv reassociation): S = Wconv @ x, per batch
    gemm_bt<0><<<dim3(6, 4, 32), 256, 0, stream>>>(
        Wconv_b, 512, 0, qT, 512, 393216, Sq, 768, 393216, 512, nullptr, nullptr, 0);
    gemm_bt<0><<<dim3(6, 4, 32), 256, 0, stream>>>(
        Wconv_b, 512, 0, kT, 512, 393216, Sk, 768, 393216, 512, nullptr, nullptr, 0);

    // projections with conv bias folded in (per-row): q1c = Sq @ Wq + bconv
    gemm_bt<2><<<dim3(4, 4, 32), 256, 0, stream>>>(
        Sq, 768, 393216, WqT, 768, 0, q1c, 512, 262144, 768, bconv, nullptr, 0);
    gemm_bt<2><<<dim3(4, 4, 32), 256, 0, stream>>>(
        Sk, 768, 393216, WkT, 768, 0, k1c, 512, 262144, 768, bconv, nullptr, 0);

    // v projection, transposed per-batch store (feature-major for PV)
    gemm_bt<1><<<dim3(8, 128, 1), 256, 0, stream>>>(
        vb, 768, 0, WvT, 768, 0, v1t, 512, 524288, 768, nullptr, nullptr, 0);

    // fused scores + mask + softmax + attn write + PV -> out1 bf16
    scores_pv_k<<<2048, 256, 0, stream>>>(
        q1c, k1c, v1t, attn, out1, mask1, mask2, scale);

    // FC + f32 residual
    gemm_bt<4><<<dim3(6, 128, 1), 256, 0, stream>>>(
        out1, 1024, 0, WfcT, 1024, 0, out2, 768, 0, 1024, nullptr, q, 768);

    // LayerNorm + nan->0 -> f32 d_out
    ln_k<<<4096, 256, 0, stream>>>(out2, gamma, beta, out);
}

// Round 4
// 792.449 us; speedup vs baseline: 1.1378x; 1.1378x over previous
//
#include <hip/hip_runtime.h>
#include <hip/hip_fp16.h>

typedef short v8s __attribute__((ext_vector_type(8)));
typedef short v4s __attribute__((ext_vector_type(4)));
typedef float v4f __attribute__((ext_vector_type(4)));

#define BM 128
#define BN 128
#define BK 64

__device__ __forceinline__ float b2f(unsigned short u) {
    union { unsigned int i; float f; } x; x.i = ((unsigned int)u) << 16; return x.f;
}
__device__ __forceinline__ unsigned short f2b(float f) {
    union { float f; unsigned int i; } x; x.f = f;
    unsigned int r = x.i + 0x7fffu + ((x.i >> 16) & 1u);
    return (unsigned short)(r >> 16);
}
__device__ __forceinline__ unsigned short f2h(float f) {
    return __half_as_ushort(__float2half(f));
}
__device__ __forceinline__ float h2f(unsigned short u) {
    return __half2float(__ushort_as_half(u));
}

// async global->LDS, 16B per lane. LDS dest is wave-uniform base + lane*16,
// so LDS layout is linear; swizzle is applied on the GLOBAL source address.
__device__ __forceinline__ void gload16(const void* g, void* l) {
    __builtin_amdgcn_global_load_lds(
        (const __attribute__((address_space(1))) void*)g,
        (__attribute__((address_space(3))) void*)l, 16, 0, 0);
}

// Generic MFMA GEMM: C[m,n] = sum_k A[m,k] * BT[n,k]  (+ epilogue). All bf16.
// LDS tiles linear [128][64] (row = 8 chunks of 16B); chunk swizzle c^=(row&7)
// on both the staging source and the ds_read side (involution).
// EPI: 1 transposed bf16 store (batch from gm, 512 rows/batch)
//      2 +bias_f32[gm], bf16 store | 4 +resid_f32[gm*ldr+gn], bf16 store
template<int EPI>
__global__ __launch_bounds__(256)
void gemm_bt(const unsigned short* __restrict__ A, int lda, long aSB,
             const unsigned short* __restrict__ BT, int ldb, long bSB,
             void* __restrict__ C, int ldc, long cSB,
             int K,
             const float* __restrict__ bias,
             const float* __restrict__ resid, int ldr)
{
    const int z = blockIdx.z;

    __shared__ unsigned short As[BM * BK];   // 16 KB
    __shared__ unsigned short Bs[BN * BK];   // 16 KB

    const int tid = threadIdx.x;
    const int wave = tid >> 6, lane = tid & 63;
    const int wm = (wave >> 1) * 64, wn = (wave & 1) * 64;
    const int quad = lane >> 4, l16 = lane & 15;
    const int sx = l16 & 7;
    const int bm = blockIdx.y * BM, bn = blockIdx.x * BN;

    // k0-invariant staging addresses (row, swizzled chunk per thread)
    const unsigned short* aP[4]; const unsigned short* bP[4];
    unsigned short* lA[4]; unsigned short* lB[4];
#pragma unroll
    for (int p = 0; p < 4; p++) {
        int idx = p * 256 + tid;
        int row = idx >> 3, c = idx & 7, cc = c ^ (row & 7);
        aP[p] = A + (long)z * aSB + (long)(bm + row) * lda + cc * 8;
        bP[p] = BT + (long)z * bSB + (long)(bn + row) * ldb + cc * 8;
        lA[p] = &As[idx * 8];
        lB[p] = &Bs[idx * 8];
    }

    v4f acc[4][4] = {};

    for (int k0 = 0; k0 < K; k0 += BK) {
#pragma unroll
        for (int p = 0; p < 4; p++) {
            gload16(aP[p] + k0, lA[p]);
            gload16(bP[p] + k0, lB[p]);
        }
        __syncthreads();   // drains vmcnt for the global_load_lds queue
#pragma unroll
        for (int ks = 0; ks < 2; ks++) {
            v8s af[4], bf[4];
#pragma unroll
            for (int i = 0; i < 4; i++) {
                const int co = ((ks * 4 + quad) ^ sx) * 8;
                af[i] = *(const v8s*)&As[(wm + i * 16 + l16) * 64 + co];
                bf[i] = *(const v8s*)&Bs[(wn + i * 16 + l16) * 64 + co];
            }
#pragma unroll
            for (int i = 0; i < 4; i++)
#pragma unroll
                for (int j = 0; j < 4; j++)
                    acc[i][j] = __builtin_amdgcn_mfma_f32_16x16x32_bf16(af[i], bf[j], acc[i][j], 0, 0, 0);
        }
        __syncthreads();
    }

    unsigned short* Cu = (unsigned short*)C + (long)z * cSB;

#pragma unroll
    for (int i = 0; i < 4; i++) {
        int rowbase = wm + i * 16 + quad * 4;
#pragma unroll
        for (int j = 0; j < 4; j++) {
            int gn = bn + wn + j * 16 + l16;
#pragma unroll
            for (int r = 0; r < 4; r++) {
                int gm = bm + rowbase + r;
                float v = acc[i][j][r];
                if (EPI == 1) {
                    int bb = gm >> 9, mm = gm & 511;
                    ((unsigned short*)C)[(long)bb * cSB + (long)gn * ldc + mm] = f2b(v);
                } else if (EPI == 2) {
                    Cu[(long)gm * ldc + gn] = f2b(v + bias[gm]);
                } else if (EPI == 4) {
                    Cu[(long)gm * ldc + gn] = f2b(v + resid[(long)gm * ldr + gn]);
                }
            }
        }
    }
}

// Fused scores + mask + softmax + attn-write + PV.
// Block = 8 waves x 16 q-rows = 128 q-rows for one (b,h); all 512 kcols.
// Phase A: K tile (512 kcols x 64 feat, 64KB) staged to LDS via gload16;
//   swapped QK^T mfma(K,Q) -> lane holds one q-row x 128 kcols, scores packed
//   f16 in u[64] (register softmax, 2 shfl per reduce).
// Phase B: V staged into the SAME 64KB region in two 64KB halves (K is dead);
//   P round-trips through wave-private 1.25KB chunks (16 rows x 80B padded ->
//   conflict-free b128). LDS total 74KB -> 2 blocks/CU = 4 waves/SIMD.
__global__ __launch_bounds__(512, 4)
void scores_pv_k(const unsigned short* __restrict__ q1c,
                 const unsigned short* __restrict__ k1c,
                 const unsigned short* __restrict__ v1t,
                 float* __restrict__ attn,
                 unsigned short* __restrict__ out1,
                 const int* __restrict__ mask1,
                 const int* __restrict__ mask2,
                 float scale)
{
    // XCD-aware swizzle: 1024 blocks = 256 (b,h) x 4 q-chunks; keep the 4
    // chunks sharing one (b,h)'s K/V slabs on the same XCD.
    const int id = blockIdx.x;
    const int logical = (id & 7) * 128 + (id >> 3);
    const int z = logical >> 2;
    const int bx = logical & 3;
    const int b = z >> 3, h = z & 7;

    const unsigned short* Qb = q1c + (long)b * 262144 + h * 64;   // (512 seq, 512 feat)
    const unsigned short* Kb = k1c + (long)b * 262144 + h * 64;
    const unsigned short* Vb = v1t + (long)b * 524288 + (long)h * 65536;  // (128 dv, 512 seq)

    __shared__ unsigned short KV[32768];   // 64KB: K tile, then V half-tiles
    __shared__ unsigned short Pl[8][640];  // 10KB: per-wave P chunk, 16 rows x 40 shorts (64B data + 16B pad)

    const int tid = threadIdx.x;
    const int wave = tid >> 6, lane = tid & 63;
    const int quad = lane >> 4, l16 = lane & 15;
    const int sx = l16 & 7;
    const int bm = bx * 128;
    const int row_l = wave * 16 + l16;
    const int qrow = bm + row_l;

    // ---- stage K: 512 rows x 64 shorts = 4096 x 16B chunks, swizzled source
    // (p < 8 : 8 x 512 threads covers the full 64KB tile — p < 4 was the
    //  round-3 bug: only rows 0..255 staged, rows 256..511 stale garbage)
#pragma unroll
    for (int p = 0; p < 8; p++) {
        int idx = p * 512 + tid;
        int row = idx >> 3, c = idx & 7, cc = c ^ (row & 7);
        gload16(Kb + (long)row * 512 + cc * 8, &KV[idx * 8]);
    }
    __syncthreads();

    // Q fragments direct from global (one-time, per-lane row)
    v8s qf0 = *(const v8s*)&Qb[(long)qrow * 512 + quad * 8];
    v8s qf1 = *(const v8s*)&Qb[(long)qrow * 512 + 32 + quad * 8];

    const int m1 = mask1[b * 512 + qrow];
    const int* m2p = mask2 + b * 512;

    unsigned int u[64];
    float mx = -1e30f;

    // ---- pass 1: QK^T from LDS, scale+mask, pack scores f16, track row max
#pragma unroll
    for (int j = 0; j < 32; j++) {
        const unsigned short* kr = &KV[(j * 16 + l16) * 64];
        v8s kf0 = *(const v8s*)&kr[(quad ^ sx) << 3];
        v8s kf1 = *(const v8s*)&kr[((4 + quad) ^ sx) << 3];
        v4f a = (v4f){0.f, 0.f, 0.f, 0.f};
        a = __builtin_amdgcn_mfma_f32_16x16x32_bf16(kf0, qf0, a, 0, 0, 0);
        a = __builtin_amdgcn_mfma_f32_16x16x32_bf16(kf1, qf1, a, 0, 0, 0);
        int4 m2v = *(const int4*)&m2p[j * 16 + quad * 4];
        float s0 = (m1 != 0 || m2v.x != 0) ? 1e-9f : a[0] * scale;
        float s1 = (m1 != 0 || m2v.y != 0) ? 1e-9f : a[1] * scale;
        float s2 = (m1 != 0 || m2v.z != 0) ? 1e-9f : a[2] * scale;
        float s3 = (m1 != 0 || m2v.w != 0) ? 1e-9f : a[3] * scale;
        mx = fmaxf(mx, fmaxf(fmaxf(s0, s1), fmaxf(s2, s3)));
        u[2 * j]     = (unsigned int)f2h(s0) | ((unsigned int)f2h(s1) << 16);
        u[2 * j + 1] = (unsigned int)f2h(s2) | ((unsigned int)f2h(s3) << 16);
    }
    mx = fmaxf(mx, __shfl_xor(mx, 16, 64));
    mx = fmaxf(mx, __shfl_xor(mx, 32, 64));

    // ---- pass 2: exp + row sum (overwrite u with packed-f16 e)
    float sum = 0.f;
#pragma unroll
    for (int j = 0; j < 32; j++) {
        float s0 = h2f((unsigned short)(u[2 * j] & 0xffffu));
        float s1 = h2f((unsigned short)(u[2 * j] >> 16));
        float s2 = h2f((unsigned short)(u[2 * j + 1] & 0xffffu));
        float s3 = h2f((unsigned short)(u[2 * j + 1] >> 16));
        float e0 = __expf(s0 - mx), e1 = __expf(s1 - mx);
        float e2 = __expf(s2 - mx), e3 = __expf(s3 - mx);
        sum += (e0 + e1) + (e2 + e3);
        u[2 * j]     = (unsigned int)f2h(e0) | ((unsigned int)f2h(e1) << 16);
        u[2 * j + 1] = (unsigned int)f2h(e2) | ((unsigned int)f2h(e3) << 16);
    }
    sum += __shfl_xor(sum, 16, 64);
    sum += __shfl_xor(sum, 32, 64);
    const float inv = 1.0f / sum;

    __syncthreads();   // all waves done reading K; region becomes V

    // ---- phase B: PV in two V halves (each 128 dv x 256 kcols = 64KB)
    float* Arow = attn + (long)z * 262144 + (long)qrow * 512;
    unsigned short* Pw = &Pl[wave][l16 * 40];   // 80B padded row
    v4f acc2[8];
#pragma unroll
    for (int t = 0; t < 8; t++) acc2[t] = (v4f){0.f, 0.f, 0.f, 0.f};

#pragma unroll
    for (int half = 0; half < 2; half++) {
        // stage V half: 4096 x 16B chunks (32 chunks per dv row), swizzled
#pragma unroll
        for (int p = 0; p < 8; p++) {
            int idx = p * 512 + tid;
            int dv = idx >> 5, c = idx & 31, cc = c ^ (dv & 7);
            gload16(Vb + (long)dv * 512 + half * 256 + cc * 8, &KV[idx * 8]);
        }
        __syncthreads();

        // 8 chunks of 32 kcols: write attn f32 + P bf16 -> wave-private LDS,
        // read P fragment back, MFMA against V fragments from LDS.
#pragma unroll
        for (int g = 0; g < 8; g++) {
            int j0 = half * 16 + 2 * g;
            float p0 = h2f((unsigned short)(u[2 * j0] & 0xffffu)) * inv;
            float p1 = h2f((unsigned short)(u[2 * j0] >> 16)) * inv;
            float p2 = h2f((unsigned short)(u[2 * j0 + 1] & 0xffffu)) * inv;
            float p3 = h2f((unsigned short)(u[2 * j0 + 1] >> 16)) * inv;
            float p4 = h2f((unsigned short)(u[2 * j0 + 2] & 0xffffu)) * inv;
            float p5 = h2f((unsigned short)(u[2 * j0 + 2] >> 16)) * inv;
            float p6 = h2f((unsigned short)(u[2 * j0 + 3] & 0xffffu)) * inv;
            float p7 = h2f((unsigned short)(u[2 * j0 + 3] >> 16)) * inv;
            float4 w0; w0.x = p0; w0.y = p1; w0.z = p2; w0.w = p3;
            float4 w1; w1.x = p4; w1.y = p5; w1.z = p6; w1.w = p7;
            *(float4*)&Arow[j0 * 16 + quad * 4] = w0;
            *(float4*)&Arow[(j0 + 1) * 16 + quad * 4] = w1;
            uint2 pr0, pr1;
            pr0.x = (unsigned int)f2b(p0) | ((unsigned int)f2b(p1) << 16);
            pr0.y = (unsigned int)f2b(p2) | ((unsigned int)f2b(p3) << 16);
            pr1.x = (unsigned int)f2b(p4) | ((unsigned int)f2b(p5) << 16);
            pr1.y = (unsigned int)f2b(p6) | ((unsigned int)f2b(p7) << 16);
            *(uint2*)&Pw[quad * 4] = pr0;        // kcols (2g)*16 + quad*4..+3
            *(uint2*)&Pw[16 + quad * 4] = pr1;   // kcols (2g+1)*16 + quad*4..+3
            v8s pf = *(const v8s*)&Pw[quad * 8]; // kcols g*32 + quad*8..+7
#pragma unroll
            for (int t = 0; t < 8; t++) {
                v8s vf = *(const v8s*)&KV[(t * 16 + l16) * 256 + (((g * 4 + quad) ^ sx) << 3)];
                acc2[t] = __builtin_amdgcn_mfma_f32_16x16x32_bf16(vf, pf, acc2[t], 0, 0, 0);
            }
        }
        __syncthreads();   // before next half overwrites V region
    }

    // out1[b][qrow][h*128 + dv], dv = t*16 + quad*4 + r
    unsigned short* Orow = out1 + (long)b * 524288 + (long)qrow * 1024 + h * 128;
#pragma unroll
    for (int t = 0; t < 8; t++) {
        v4s o;
        o[0] = (short)f2b(acc2[t][0]); o[1] = (short)f2b(acc2[t][1]);
        o[2] = (short)f2b(acc2[t][2]); o[3] = (short)f2b(acc2[t][3]);
        *(v4s*)&Orow[t * 16 + quad * 4] = o;
    }
}

// all weight prep (4 transposes f32->bf16^T + Wconv cast) + q/k/v bf16 casts
__global__ __launch_bounds__(256)
void prep_k(const float* __restrict__ Wq, const float* __restrict__ Wk,
            const float* __restrict__ Wv, const float* __restrict__ Wfc,
            const float* __restrict__ Wconv,
            const float* __restrict__ qf, const float* __restrict__ kf,
            const float* __restrict__ vf,
            unsigned short* __restrict__ WqT, unsigned short* __restrict__ WkT,
            unsigned short* __restrict__ WvT, unsigned short* __restrict__ WfcT,
            unsigned short* __restrict__ Wconv_b,
            unsigned short* __restrict__ qb, unsigned short* __restrict__ kb,
            unsigned short* __restrict__ vb)
{
    __shared__ float t[32][33];
    int blk = blockIdx.x, tid = threadIdx.x;
    if (blk < 2304) {
        const float* src; unsigned short* dst; int K, N, local;
        if (blk < 384)       { src = Wq;  dst = WqT;  K = 768;  N = 512;  local = blk; }
        else if (blk < 768)  { src = Wk;  dst = WkT;  K = 768;  N = 512;  local = blk - 384; }
        else if (blk < 1536) { src = Wv;  dst = WvT;  K = 768;  N = 1024; local = blk - 768; }
        else                 { src = Wfc; dst = WfcT; K = 1024; N = 768;  local = blk - 1536; }
        int nb32 = N >> 5;
        int kb32 = (local / nb32) * 32, nb = (local % nb32) * 32;
        int tx = tid & 31, ty = tid >> 5;
#pragma unroll
        for (int i = 0; i < 32; i += 8)
            t[ty + i][tx] = src[(long)(kb32 + ty + i) * N + nb + tx];
        __syncthreads();
#pragma unroll
        for (int i = 0; i < 32; i += 8)
            dst[(long)(nb + ty + i) * K + kb32 + tx] = f2b(t[tx][ty + i]);
    } else if (blk < 3328) {
        int i = (blk - 2304) * 256 + tid;   // Wconv: 512*512 = 262144
        Wconv_b[i] = f2b(Wconv[i]);
    } else {
        long t0 = (long)(blk - 3328) * 4096 + (long)tid * 16;
        const float* src; unsigned short* dst; long i = t0;
        if (t0 < 12582912L)       { src = qf; dst = qb; }
        else if (t0 < 25165824L)  { src = kf; dst = kb; i = t0 - 12582912L; }
        else                      { src = vf; dst = vb; i = t0 - 25165824L; }
        float4 a = *(const float4*)&src[i];
        float4 b4 = *(const float4*)&src[i + 4];
        float4 c4 = *(const float4*)&src[i + 8];
        float4 d4 = *(const float4*)&src[i + 12];
        v8s r0, r1;
        r0[0] = (short)f2b(a.x);  r0[1] = (short)f2b(a.y);
        r0[2] = (short)f2b(a.z);  r0[3] = (short)f2b(a.w);
        r0[4] = (short)f2b(b4.x); r0[5] = (short)f2b(b4.y);
        r0[6] = (short)f2b(b4.z); r0[7] = (short)f2b(b4.w);
        r1[0] = (short)f2b(c4.x); r1[1] = (short)f2b(c4.y);
        r1[2] = (short)f2b(c4.z); r1[3] = (short)f2b(c4.w);
        r1[4] = (short)f2b(d4.x); r1[5] = (short)f2b(d4.y);
        r1[6] = (short)f2b(d4.z); r1[7] = (short)f2b(d4.w);
        *(v8s*)&dst[i] = r0;
        *(v8s*)&dst[i + 8] = r1;
    }
}

// LayerNorm over rows of 768 (bf16 in, f32 gamma/beta, f32 out) + nan->0
__global__ __launch_bounds__(256)
void ln_k(const unsigned short* __restrict__ x,
          const float* __restrict__ gamma,
          const float* __restrict__ beta,
          float* __restrict__ out)
{
    long row = (long)blockIdx.x * 4 + (threadIdx.x >> 6);
    int lane = threadIdx.x & 63;
    const unsigned short* p = x + row * 768;
    v8s a = *(const v8s*)&p[lane * 8];          // cols lane*8 .. +7
    v4s b4 = *(const v4s*)&p[512 + lane * 4];   // cols 512+lane*4 .. +3
    float v[12];
    float s = 0.f, s2 = 0.f;
#pragma unroll
    for (int j = 0; j < 8; j++) { v[j] = b2f((unsigned short)a[j]); s += v[j]; s2 += v[j] * v[j]; }
#pragma unroll
    for (int j = 0; j < 4; j++) { v[8 + j] = b2f((unsigned short)b4[j]); s += v[8 + j]; s2 += v[8 + j] * v[8 + j]; }
#pragma unroll
    for (int o = 32; o > 0; o >>= 1) { s += __shfl_xor(s, o, 64); s2 += __shfl_xor(s2, o, 64); }
    float mean = s * (1.0f / 768.0f);
    float var = s2 * (1.0f / 768.0f) - mean * mean;
    if (!(var >= 0.f)) var = 0.f;
    float rstd = rsqrtf(var + 1e-6f);
    float o12[12];
#pragma unroll
    for (int j = 0; j < 8; j++) {
        int c = lane * 8 + j;
        float o = (v[j] - mean) * rstd * gamma[c] + beta[c];
        union { float f; unsigned int i; } uu; uu.f = o;
        if ((uu.i & 0x7FFFFFFFu) > 0x7F800000u) uu.f = 0.f;
        o12[j] = uu.f;
    }
#pragma unroll
    for (int j = 0; j < 4; j++) {
        int c = 512 + lane * 4 + j;
        float o = (v[8 + j] - mean) * rstd * gamma[c] + beta[c];
        union { float f; unsigned int i; } uu; uu.f = o;
        if ((uu.i & 0x7FFFFFFFu) > 0x7F800000u) uu.f = 0.f;
        o12[8 + j] = uu.f;
    }
    float4 f0; f0.x = o12[0]; f0.y = o12[1]; f0.z = o12[2]; f0.w = o12[3];
    float4 f1; f1.x = o12[4]; f1.y = o12[5]; f1.z = o12[6]; f1.w = o12[7];
    float4 f2; f2.x = o12[8]; f2.y = o12[9]; f2.z = o12[10]; f2.w = o12[11];
    *(float4*)&out[row * 768 + lane * 8] = f0;
    *(float4*)&out[row * 768 + lane * 8 + 4] = f1;
    *(float4*)&out[row * 768 + 512 + lane * 4] = f2;
}

extern "C" void kernel_launch(void* const* d_in, const int* in_sizes, int n_in,
                              void* d_out, int out_size, void* d_ws, size_t ws_size,
                              hipStream_t stream)
{
    // B=32, L=512, D_EMB=768, D_K=512, D_V=1024, H=8 — all I/O float32
    const float* q     = (const float*)d_in[0];
    const float* k     = (const float*)d_in[1];
    const float* v     = (const float*)d_in[2];
    const float* Wq    = (const float*)d_in[3];
    const float* Wk    = (const float*)d_in[4];
    const float* Wv    = (const float*)d_in[5];
    const float* Wconv = (const float*)d_in[6];
    const float* bconv = (const float*)d_in[7];
    const float* Wfc   = (const float*)d_in[8];
    const float* gamma = (const float*)d_in[9];
    const float* beta  = (const float*)d_in[10];
    const int* mask1   = (const int*)d_in[11];
    const int* mask2   = (const int*)d_in[12];

    float* out  = (float*)d_out;               // (32,512,768) f32
    float* attn = out + 12582912;              // (32,8,512,512) f32

    // ws layout (ushort elems)
    unsigned short* ws = (unsigned short*)d_ws;
    unsigned short* WqT     = ws;              // 512x768
    unsigned short* WkT     = ws + 393216;     // 512x768
    unsigned short* WvT     = ws + 786432;     // 1024x768
    unsigned short* WfcT    = ws + 1572864;    // 768x1024
    unsigned short* Wconv_b = ws + 2359296;    // 512x512
    unsigned short* q1c     = ws + 2621440;    // (32,512,512)
    unsigned short* k1c     = ws + 11010048;   // (32,512,512)
    unsigned short* v1t     = ws + 19398656;   // (32,1024,512)  [.. 36175872)
    unsigned short* out2    = ws + 19398656;   // (32,512,768)  aliases v1t (dead after scores_pv)

    // scratch in d_out's attn region (268 MB) — all dead before scores_pv writes attn
    unsigned short* aScr = (unsigned short*)attn;
    unsigned short* q1t = aScr;                // (32,512,512) feature-major
    unsigned short* k1t = aScr + 8388608;      // (32,512,512)
    unsigned short* qb  = aScr + 16777216;     // (32,512,768) bf16 cast of q
    unsigned short* kb  = aScr + 29360128;     // bf16 cast of k
    unsigned short* vb  = aScr + 41943040;     // bf16 cast of v  [.. 54525952)
    // out1 in d_out's "out" region; consumed by FC before ln_k overwrites it.
    unsigned short* out1 = (unsigned short*)out;   // (32,512,1024) bf16

    // all weight prep + q/k/v bf16 casts in one dispatch
    prep_k<<<12544, 256, 0, stream>>>(Wq, Wk, Wv, Wfc, Wconv, q, k, v,
                                      WqT, WkT, WvT, WfcT, Wconv_b, qb, kb, vb);

    const float scale = 0.04419417382415922f;  // 1/sqrt(512)

    // projections (all bf16), transposed per-batch store (feature-major)
    gemm_bt<1><<<dim3(4, 128, 1), 256, 0, stream>>>(
        qb, 768, 0, WqT, 768, 0, q1t, 512, 262144, 768, nullptr, nullptr, 0);
    gemm_bt<1><<<dim3(4, 128, 1), 256, 0, stream>>>(
        kb, 768, 0, WkT, 768, 0, k1t, 512, 262144, 768, nullptr, nullptr, 0);
    gemm_bt<1><<<dim3(8, 128, 1), 256, 0, stream>>>(
        vb, 768, 0, WvT, 768, 0, v1t, 512, 524288, 768, nullptr, nullptr, 0);

    // conv over seq axis: q1c[b] = Wconv_b (o x c) x q1t[b]^T + bconv
    gemm_bt<2><<<dim3(4, 4, 32), 256, 0, stream>>>(
        Wconv_b, 512, 0, q1t, 512, 262144, q1c, 512, 262144, 512, bconv, nullptr, 0);
    gemm_bt<2><<<dim3(4, 4, 32), 256, 0, stream>>>(
        Wconv_b, 512, 0, k1t, 512, 262144, k1c, 512, 262144, 512, bconv, nullptr, 0);

    // fused scores + mask + softmax + attn write + PV -> out1 bf16
    scores_pv_k<<<1024, 512, 0, stream>>>(
        q1c, k1c, v1t, attn, out1, mask1, mask2, scale);

    // FC + f32 residual
    gemm_bt<4><<<dim3(6, 128, 1), 256, 0, stream>>>(
        out1, 1024, 0, WfcT, 1024, 0, out2, 768, 0, 1024, nullptr, q, 768);

    // LayerNorm + nan->0 -> f32 d_out
    ln_k<<<4096, 256, 0, stream>>>(out2, gamma, beta, out);
}

// Round 5
// 708.766 us; speedup vs baseline: 1.2722x; 1.1181x over previous
//
#include <hip/hip_runtime.h>
#include <hip/hip_fp16.h>

typedef short v8s __attribute__((ext_vector_type(8)));
typedef short v4s __attribute__((ext_vector_type(4)));
typedef float v4f __attribute__((ext_vector_type(4)));

#define BM 128
#define BN 128
#define BK 64

__device__ __forceinline__ float b2f(unsigned short u) {
    union { unsigned int i; float f; } x; x.i = ((unsigned int)u) << 16; return x.f;
}
__device__ __forceinline__ unsigned short f2b(float f) {
    union { float f; unsigned int i; } x; x.f = f;
    unsigned int r = x.i + 0x7fffu + ((x.i >> 16) & 1u);
    return (unsigned short)(r >> 16);
}

// async global->LDS, 16B per lane. LDS dest is wave-uniform base + lane*16,
// so LDS layout is linear; swizzle is applied on the GLOBAL source address.
__device__ __forceinline__ void gload16(const void* g, void* l) {
    __builtin_amdgcn_global_load_lds(
        (const __attribute__((address_space(1))) void*)g,
        (__attribute__((address_space(3))) void*)l, 16, 0, 0);
}

// Generic MFMA GEMM: C[m,n] = sum_k A[m,k] * BT[n,k]  (+ epilogue). All bf16.
// LDS tiles linear [128][64] (row = 8 chunks of 16B); chunk swizzle c^=(row&7)
// on both the staging source and the ds_read side (involution).
// EPI: 1 transposed bf16 store (batch from gm, 512 rows/batch)
//      2 +bias_f32[gm], bf16 store | 4 +resid_f32[gm*ldr+gn], bf16 store
template<int EPI>
__global__ __launch_bounds__(256)
void gemm_bt(const unsigned short* __restrict__ A, int lda, long aSB,
             const unsigned short* __restrict__ BT, int ldb, long bSB,
             void* __restrict__ C, int ldc, long cSB,
             int K,
             const float* __restrict__ bias,
             const float* __restrict__ resid, int ldr)
{
    const int z = blockIdx.z;

    __shared__ unsigned short As[BM * BK];   // 16 KB
    __shared__ unsigned short Bs[BN * BK];   // 16 KB

    const int tid = threadIdx.x;
    const int wave = tid >> 6, lane = tid & 63;
    const int wm = (wave >> 1) * 64, wn = (wave & 1) * 64;
    const int quad = lane >> 4, l16 = lane & 15;
    const int sx = l16 & 7;
    const int bm = blockIdx.y * BM, bn = blockIdx.x * BN;

    // k0-invariant staging addresses (row, swizzled chunk per thread)
    const unsigned short* aP[4]; const unsigned short* bP[4];
    unsigned short* lA[4]; unsigned short* lB[4];
#pragma unroll
    for (int p = 0; p < 4; p++) {
        int idx = p * 256 + tid;
        int row = idx >> 3, c = idx & 7, cc = c ^ (row & 7);
        aP[p] = A + (long)z * aSB + (long)(bm + row) * lda + cc * 8;
        bP[p] = BT + (long)z * bSB + (long)(bn + row) * ldb + cc * 8;
        lA[p] = &As[idx * 8];
        lB[p] = &Bs[idx * 8];
    }

    v4f acc[4][4] = {};

    for (int k0 = 0; k0 < K; k0 += BK) {
#pragma unroll
        for (int p = 0; p < 4; p++) {
            gload16(aP[p] + k0, lA[p]);
            gload16(bP[p] + k0, lB[p]);
        }
        __syncthreads();   // drains vmcnt for the global_load_lds queue
#pragma unroll
        for (int ks = 0; ks < 2; ks++) {
            v8s af[4], bf[4];
#pragma unroll
            for (int i = 0; i < 4; i++) {
                const int co = ((ks * 4 + quad) ^ sx) * 8;
                af[i] = *(const v8s*)&As[(wm + i * 16 + l16) * 64 + co];
                bf[i] = *(const v8s*)&Bs[(wn + i * 16 + l16) * 64 + co];
            }
#pragma unroll
            for (int i = 0; i < 4; i++)
#pragma unroll
                for (int j = 0; j < 4; j++)
                    acc[i][j] = __builtin_amdgcn_mfma_f32_16x16x32_bf16(af[i], bf[j], acc[i][j], 0, 0, 0);
        }
        __syncthreads();
    }

    unsigned short* Cu = (unsigned short*)C + (long)z * cSB;

#pragma unroll
    for (int i = 0; i < 4; i++) {
        int rowbase = wm + i * 16 + quad * 4;
#pragma unroll
        for (int j = 0; j < 4; j++) {
            int gn = bn + wn + j * 16 + l16;
#pragma unroll
            for (int r = 0; r < 4; r++) {
                int gm = bm + rowbase + r;
                float v = acc[i][j][r];
                if (EPI == 1) {
                    int bb = gm >> 9, mm = gm & 511;
                    ((unsigned short*)C)[(long)bb * cSB + (long)gn * ldc + mm] = f2b(v);
                } else if (EPI == 2) {
                    Cu[(long)gm * ldc + gn] = f2b(v + bias[gm]);
                } else if (EPI == 4) {
                    Cu[(long)gm * ldc + gn] = f2b(v + resid[(long)gm * ldr + gn]);
                }
            }
        }
    }
}

// Fused scores + mask + softmax + attn-write + PV, ZERO persistent score state.
// Block = 8 waves x 16 q-rows = 128 q-rows for one (b,h); all 512 kcols.
// Sweep 1: K staged in 4 tiles of 128 kcols (16KB LDS); swapped QK^T mfma(K,Q)
//   -> lane holds one q-row; ONLINE (m, sum) only — 2 scalars/lane, no u[64]
//   (round-4's u[64] spilled to scratch: 540MB of hidden HBM traffic).
// Sweep 2: per tile restage K (L2-hot) + V tile (128 dv x 128 kcols, 32KB);
//   recompute QK^T per 32-col group, exp*inv, write attn f32, pack bf16 P into
//   wave-private padded Pw (conflict-free), 8 PV MFMAs from LDS V.
// LDS 60KB -> 2 blocks/CU; regs ~112 -> no spill at the 128 cap.
__global__ __launch_bounds__(512, 4)
void scores_pv_k(const unsigned short* __restrict__ q1c,
                 const unsigned short* __restrict__ k1c,
                 const unsigned short* __restrict__ v1t,
                 float* __restrict__ attn,
                 unsigned short* __restrict__ out1,
                 const int* __restrict__ mask1,
                 const int* __restrict__ mask2,
                 float scale)
{
    // XCD-aware swizzle: 1024 blocks = 256 (b,h) x 4 q-chunks; keep the 4
    // chunks sharing one (b,h)'s K/V slabs on the same XCD.
    const int id = blockIdx.x;
    const int logical = (id & 7) * 128 + (id >> 3);
    const int z = logical >> 2;
    const int bx = logical & 3;
    const int b = z >> 3, h = z & 7;

    const unsigned short* Qb = q1c + (long)b * 262144 + h * 64;   // (512 seq, 512 feat)
    const unsigned short* Kb = k1c + (long)b * 262144 + h * 64;
    const unsigned short* Vb = v1t + (long)b * 524288 + (long)h * 65536;  // (128 dv, 512 seq)

    __shared__ unsigned short KA[128 * 64];    // 16KB: K tile (128 kcols x 64 feat)
    __shared__ unsigned short VB[128 * 128];   // 32KB: V tile (128 dv x 128 kcols)
    __shared__ unsigned short Pl[8][640];      // 10KB: per-wave P chunk, 16 rows x 40 shorts
    __shared__ int m2s[512];                   // 2KB

    const int tid = threadIdx.x;
    const int wave = tid >> 6, lane = tid & 63;
    const int quad = lane >> 4, l16 = lane & 15;
    const int sx = l16 & 7;
    const int bm = bx * 128;
    const int row_l = wave * 16 + l16;
    const int qrow = bm + row_l;

    m2s[tid] = mask2[b * 512 + tid];

    // Q fragments direct from global (one-time, per-lane row)
    v8s qf0 = *(const v8s*)&Qb[(long)qrow * 512 + quad * 8];
    v8s qf1 = *(const v8s*)&Qb[(long)qrow * 512 + 32 + quad * 8];
    const int m1 = mask1[b * 512 + qrow];

    float m_l = -1e30f, sum = 0.f;

    // ---- sweep 1: online softmax stats (no score storage)
    for (int kt = 0; kt < 4; kt++) {
#pragma unroll
        for (int p = 0; p < 2; p++) {
            int idx = p * 512 + tid;
            int row = idx >> 3, c = idx & 7, cc = c ^ (row & 7);
            gload16(Kb + (long)(kt * 128 + row) * 512 + cc * 8, &KA[idx * 8]);
        }
        __syncthreads();
#pragma unroll
        for (int jl = 0; jl < 8; jl++) {
            const unsigned short* kr = &KA[(jl * 16 + l16) * 64];
            v8s kf0 = *(const v8s*)&kr[(quad ^ sx) << 3];
            v8s kf1 = *(const v8s*)&kr[((4 + quad) ^ sx) << 3];
            v4f a = (v4f){0.f, 0.f, 0.f, 0.f};
            a = __builtin_amdgcn_mfma_f32_16x16x32_bf16(kf0, qf0, a, 0, 0, 0);
            a = __builtin_amdgcn_mfma_f32_16x16x32_bf16(kf1, qf1, a, 0, 0, 0);
            int j = kt * 8 + jl;
            int4 m2v = *(const int4*)&m2s[j * 16 + quad * 4];
            float s0 = (m1 != 0 || m2v.x != 0) ? 1e-9f : a[0] * scale;
            float s1 = (m1 != 0 || m2v.y != 0) ? 1e-9f : a[1] * scale;
            float s2 = (m1 != 0 || m2v.z != 0) ? 1e-9f : a[2] * scale;
            float s3 = (m1 != 0 || m2v.w != 0) ? 1e-9f : a[3] * scale;
            float m4 = fmaxf(fmaxf(s0, s1), fmaxf(s2, s3));
            float mn = fmaxf(m_l, m4);
            sum = sum * __expf(m_l - mn)
                + (__expf(s0 - mn) + __expf(s1 - mn))
                + (__expf(s2 - mn) + __expf(s3 - mn));
            m_l = mn;
        }
        __syncthreads();   // before restaging KA
    }
    // cross-quad reduce (lanes l16, l16+16, +32, +48 share a q-row)
    float mx = fmaxf(m_l, __shfl_xor(m_l, 16, 64));
    mx = fmaxf(mx, __shfl_xor(mx, 32, 64));
    sum *= __expf(m_l - mx);
    sum += __shfl_xor(sum, 16, 64);
    sum += __shfl_xor(sum, 32, 64);
    const float inv = 1.0f / sum;

    // ---- sweep 2: recompute scores per tile, write attn, PV
    float* Arow = attn + (long)z * 262144 + (long)qrow * 512;
    unsigned short* Pw = &Pl[wave][l16 * 40];   // 80B padded row
    v4f acc2[8];
#pragma unroll
    for (int t = 0; t < 8; t++) acc2[t] = (v4f){0.f, 0.f, 0.f, 0.f};

    for (int kt = 0; kt < 4; kt++) {
#pragma unroll
        for (int p = 0; p < 2; p++) {
            int idx = p * 512 + tid;
            int row = idx >> 3, c = idx & 7, cc = c ^ (row & 7);
            gload16(Kb + (long)(kt * 128 + row) * 512 + cc * 8, &KA[idx * 8]);
        }
#pragma unroll
        for (int p = 0; p < 4; p++) {
            int idx = p * 512 + tid;
            int dv = idx >> 4, c = idx & 15, cc = c ^ (dv & 7);
            gload16(Vb + (long)dv * 512 + kt * 128 + cc * 8, &VB[idx * 8]);
        }
        __syncthreads();

#pragma unroll
        for (int g = 0; g < 4; g++) {
            float p8[8];
#pragma unroll
            for (int t2 = 0; t2 < 2; t2++) {
                int jl = g * 2 + t2;
                const unsigned short* kr = &KA[(jl * 16 + l16) * 64];
                v8s kf0 = *(const v8s*)&kr[(quad ^ sx) << 3];
                v8s kf1 = *(const v8s*)&kr[((4 + quad) ^ sx) << 3];
                v4f a = (v4f){0.f, 0.f, 0.f, 0.f};
                a = __builtin_amdgcn_mfma_f32_16x16x32_bf16(kf0, qf0, a, 0, 0, 0);
                a = __builtin_amdgcn_mfma_f32_16x16x32_bf16(kf1, qf1, a, 0, 0, 0);
                int j = kt * 8 + jl;
                int4 m2v = *(const int4*)&m2s[j * 16 + quad * 4];
                float s0 = (m1 != 0 || m2v.x != 0) ? 1e-9f : a[0] * scale;
                float s1 = (m1 != 0 || m2v.y != 0) ? 1e-9f : a[1] * scale;
                float s2 = (m1 != 0 || m2v.z != 0) ? 1e-9f : a[2] * scale;
                float s3 = (m1 != 0 || m2v.w != 0) ? 1e-9f : a[3] * scale;
                p8[t2 * 4 + 0] = __expf(s0 - mx) * inv;
                p8[t2 * 4 + 1] = __expf(s1 - mx) * inv;
                p8[t2 * 4 + 2] = __expf(s2 - mx) * inv;
                p8[t2 * 4 + 3] = __expf(s3 - mx) * inv;
            }
            int j0 = kt * 8 + g * 2;
            float4 w0; w0.x = p8[0]; w0.y = p8[1]; w0.z = p8[2]; w0.w = p8[3];
            float4 w1; w1.x = p8[4]; w1.y = p8[5]; w1.z = p8[6]; w1.w = p8[7];
            *(float4*)&Arow[j0 * 16 + quad * 4] = w0;
            *(float4*)&Arow[(j0 + 1) * 16 + quad * 4] = w1;
            uint2 pr0, pr1;
            pr0.x = (unsigned int)f2b(p8[0]) | ((unsigned int)f2b(p8[1]) << 16);
            pr0.y = (unsigned int)f2b(p8[2]) | ((unsigned int)f2b(p8[3]) << 16);
            pr1.x = (unsigned int)f2b(p8[4]) | ((unsigned int)f2b(p8[5]) << 16);
            pr1.y = (unsigned int)f2b(p8[6]) | ((unsigned int)f2b(p8[7]) << 16);
            *(uint2*)&Pw[quad * 4] = pr0;        // kcols (j0)*16 + quad*4..+3
            *(uint2*)&Pw[16 + quad * 4] = pr1;   // kcols (j0+1)*16 + quad*4..+3
            v8s pf = *(const v8s*)&Pw[quad * 8]; // kcols g*32 + quad*8..+7 (local)
#pragma unroll
            for (int t = 0; t < 8; t++) {
                v8s vf = *(const v8s*)&VB[(t * 16 + l16) * 128 + (((g * 4 + quad) ^ sx) << 3)];
                acc2[t] = __builtin_amdgcn_mfma_f32_16x16x32_bf16(vf, pf, acc2[t], 0, 0, 0);
            }
        }
        __syncthreads();   // before next tile overwrites KA/VB
    }

    // out1[b][qrow][h*128 + dv], dv = t*16 + quad*4 + r
    unsigned short* Orow = out1 + (long)b * 524288 + (long)qrow * 1024 + h * 128;
#pragma unroll
    for (int t = 0; t < 8; t++) {
        v4s o;
        o[0] = (short)f2b(acc2[t][0]); o[1] = (short)f2b(acc2[t][1]);
        o[2] = (short)f2b(acc2[t][2]); o[3] = (short)f2b(acc2[t][3]);
        *(v4s*)&Orow[t * 16 + quad * 4] = o;
    }
}

// all weight prep (4 transposes f32->bf16^T + Wconv cast) + q/k/v bf16 casts
__global__ __launch_bounds__(256)
void prep_k(const float* __restrict__ Wq, const float* __restrict__ Wk,
            const float* __restrict__ Wv, const float* __restrict__ Wfc,
            const float* __restrict__ Wconv,
            const float* __restrict__ qf, const float* __restrict__ kf,
            const float* __restrict__ vf,
            unsigned short* __restrict__ WqT, unsigned short* __restrict__ WkT,
            unsigned short* __restrict__ WvT, unsigned short* __restrict__ WfcT,
            unsigned short* __restrict__ Wconv_b,
            unsigned short* __restrict__ qb, unsigned short* __restrict__ kb,
            unsigned short* __restrict__ vb)
{
    __shared__ float t[32][33];
    int blk = blockIdx.x, tid = threadIdx.x;
    if (blk < 2304) {
        const float* src; unsigned short* dst; int K, N, local;
        if (blk < 384)       { src = Wq;  dst = WqT;  K = 768;  N = 512;  local = blk; }
        else if (blk < 768)  { src = Wk;  dst = WkT;  K = 768;  N = 512;  local = blk - 384; }
        else if (blk < 1536) { src = Wv;  dst = WvT;  K = 768;  N = 1024; local = blk - 768; }
        else                 { src = Wfc; dst = WfcT; K = 1024; N = 768;  local = blk - 1536; }
        int nb32 = N >> 5;
        int kb32 = (local / nb32) * 32, nb = (local % nb32) * 32;
        int tx = tid & 31, ty = tid >> 5;
#pragma unroll
        for (int i = 0; i < 32; i += 8)
            t[ty + i][tx] = src[(long)(kb32 + ty + i) * N + nb + tx];
        __syncthreads();
#pragma unroll
        for (int i = 0; i < 32; i += 8)
            dst[(long)(nb + ty + i) * K + kb32 + tx] = f2b(t[tx][ty + i]);
    } else if (blk < 3328) {
        int i = (blk - 2304) * 256 + tid;   // Wconv: 512*512 = 262144
        Wconv_b[i] = f2b(Wconv[i]);
    } else {
        long t0 = (long)(blk - 3328) * 4096 + (long)tid * 16;
        const float* src; unsigned short* dst; long i = t0;
        if (t0 < 12582912L)       { src = qf; dst = qb; }
        else if (t0 < 25165824L)  { src = kf; dst = kb; i = t0 - 12582912L; }
        else                      { src = vf; dst = vb; i = t0 - 25165824L; }
        float4 a = *(const float4*)&src[i];
        float4 b4 = *(const float4*)&src[i + 4];
        float4 c4 = *(const float4*)&src[i + 8];
        float4 d4 = *(const float4*)&src[i + 12];
        v8s r0, r1;
        r0[0] = (short)f2b(a.x);  r0[1] = (short)f2b(a.y);
        r0[2] = (short)f2b(a.z);  r0[3] = (short)f2b(a.w);
        r0[4] = (short)f2b(b4.x); r0[5] = (short)f2b(b4.y);
        r0[6] = (short)f2b(b4.z); r0[7] = (short)f2b(b4.w);
        r1[0] = (short)f2b(c4.x); r1[1] = (short)f2b(c4.y);
        r1[2] = (short)f2b(c4.z); r1[3] = (short)f2b(c4.w);
        r1[4] = (short)f2b(d4.x); r1[5] = (short)f2b(d4.y);
        r1[6] = (short)f2b(d4.z); r1[7] = (short)f2b(d4.w);
        *(v8s*)&dst[i] = r0;
        *(v8s*)&dst[i + 8] = r1;
    }
}

// LayerNorm over rows of 768 (bf16 in, f32 gamma/beta, f32 out) + nan->0
__global__ __launch_bounds__(256)
void ln_k(const unsigned short* __restrict__ x,
          const float* __restrict__ gamma,
          const float* __restrict__ beta,
          float* __restrict__ out)
{
    long row = (long)blockIdx.x * 4 + (threadIdx.x >> 6);
    int lane = threadIdx.x & 63;
    const unsigned short* p = x + row * 768;
    v8s a = *(const v8s*)&p[lane * 8];          // cols lane*8 .. +7
    v4s b4 = *(const v4s*)&p[512 + lane * 4];   // cols 512+lane*4 .. +3
    float v[12];
    float s = 0.f, s2 = 0.f;
#pragma unroll
    for (int j = 0; j < 8; j++) { v[j] = b2f((unsigned short)a[j]); s += v[j]; s2 += v[j] * v[j]; }
#pragma unroll
    for (int j = 0; j < 4; j++) { v[8 + j] = b2f((unsigned short)b4[j]); s += v[8 + j]; s2 += v[8 + j] * v[8 + j]; }
#pragma unroll
    for (int o = 32; o > 0; o >>= 1) { s += __shfl_xor(s, o, 64); s2 += __shfl_xor(s2, o, 64); }
    float mean = s * (1.0f / 768.0f);
    float var = s2 * (1.0f / 768.0f) - mean * mean;
    if (!(var >= 0.f)) var = 0.f;
    float rstd = rsqrtf(var + 1e-6f);
    float o12[12];
#pragma unroll
    for (int j = 0; j < 8; j++) {
        int c = lane * 8 + j;
        float o = (v[j] - mean) * rstd * gamma[c] + beta[c];
        union { float f; unsigned int i; } uu; uu.f = o;
        if ((uu.i & 0x7FFFFFFFu) > 0x7F800000u) uu.f = 0.f;
        o12[j] = uu.f;
    }
#pragma unroll
    for (int j = 0; j < 4; j++) {
        int c = 512 + lane * 4 + j;
        float o = (v[8 + j] - mean) * rstd * gamma[c] + beta[c];
        union { float f; unsigned int i; } uu; uu.f = o;
        if ((uu.i & 0x7FFFFFFFu) > 0x7F800000u) uu.f = 0.f;
        o12[8 + j] = uu.f;
    }
    float4 f0; f0.x = o12[0]; f0.y = o12[1]; f0.z = o12[2]; f0.w = o12[3];
    float4 f1; f1.x = o12[4]; f1.y = o12[5]; f1.z = o12[6]; f1.w = o12[7];
    float4 f2; f2.x = o12[8]; f2.y = o12[9]; f2.z = o12[10]; f2.w = o12[11];
    *(float4*)&out[row * 768 + lane * 8] = f0;
    *(float4*)&out[row * 768 + lane * 8 + 4] = f1;
    *(float4*)&out[row * 768 + 512 + lane * 4] = f2;
}

extern "C" void kernel_launch(void* const* d_in, const int* in_sizes, int n_in,
                              void* d_out, int out_size, void* d_ws, size_t ws_size,
                              hipStream_t stream)
{
    // B=32, L=512, D_EMB=768, D_K=512, D_V=1024, H=8 — all I/O float32
    const float* q     = (const float*)d_in[0];
    const float* k     = (const float*)d_in[1];
    const float* v     = (const float*)d_in[2];
    const float* Wq    = (const float*)d_in[3];
    const float* Wk    = (const float*)d_in[4];
    const float* Wv    = (const float*)d_in[5];
    const float* Wconv = (const float*)d_in[6];
    const float* bconv = (const float*)d_in[7];
    const float* Wfc   = (const float*)d_in[8];
    const float* gamma = (const float*)d_in[9];
    const float* beta  = (const float*)d_in[10];
    const int* mask1   = (const int*)d_in[11];
    const int* mask2   = (const int*)d_in[12];

    float* out  = (float*)d_out;               // (32,512,768) f32
    float* attn = out + 12582912;              // (32,8,512,512) f32

    // ws layout (ushort elems)
    unsigned short* ws = (unsigned short*)d_ws;
    unsigned short* WqT     = ws;              // 512x768
    unsigned short* WkT     = ws + 393216;     // 512x768
    unsigned short* WvT     = ws + 786432;     // 1024x768
    unsigned short* WfcT    = ws + 1572864;    // 768x1024
    unsigned short* Wconv_b = ws + 2359296;    // 512x512
    unsigned short* q1c     = ws + 2621440;    // (32,512,512)
    unsigned short* k1c     = ws + 11010048;   // (32,512,512)
    unsigned short* v1t     = ws + 19398656;   // (32,1024,512)  [.. 36175872)
    unsigned short* out2    = ws + 19398656;   // (32,512,768)  aliases v1t (dead after scores_pv)

    // scratch in d_out's attn region (268 MB) — all dead before scores_pv writes attn
    unsigned short* aScr = (unsigned short*)attn;
    unsigned short* q1t = aScr;                // (32,512,512) feature-major
    unsigned short* k1t = aScr + 8388608;      // (32,512,512)
    unsigned short* qb  = aScr + 16777216;     // (32,512,768) bf16 cast of q
    unsigned short* kb  = aScr + 29360128;     // bf16 cast of k
    unsigned short* vb  = aScr + 41943040;     // bf16 cast of v  [.. 54525952)
    // out1 in d_out's "out" region; consumed by FC before ln_k overwrites it.
    unsigned short* out1 = (unsigned short*)out;   // (32,512,1024) bf16

    // all weight prep + q/k/v bf16 casts in one dispatch
    prep_k<<<12544, 256, 0, stream>>>(Wq, Wk, Wv, Wfc, Wconv, q, k, v,
                                      WqT, WkT, WvT, WfcT, Wconv_b, qb, kb, vb);

    const float scale = 0.04419417382415922f;  // 1/sqrt(512)

    // projections (all bf16), transposed per-batch store (feature-major)
    gemm_bt<1><<<dim3(4, 128, 1), 256, 0, stream>>>(
        qb, 768, 0, WqT, 768, 0, q1t, 512, 262144, 768, nullptr, nullptr, 0);
    gemm_bt<1><<<dim3(4, 128, 1), 256, 0, stream>>>(
        kb, 768, 0, WkT, 768, 0, k1t, 512, 262144, 768, nullptr, nullptr, 0);
    gemm_bt<1><<<dim3(8, 128, 1), 256, 0, stream>>>(
        vb, 768, 0, WvT, 768, 0, v1t, 512, 524288, 768, nullptr, nullptr, 0);

    // conv over seq axis: q1c[b] = Wconv_b (o x c) x q1t[b]^T + bconv
    gemm_bt<2><<<dim3(4, 4, 32), 256, 0, stream>>>(
        Wconv_b, 512, 0, q1t, 512, 262144, q1c, 512, 262144, 512, bconv, nullptr, 0);
    gemm_bt<2><<<dim3(4, 4, 32), 256, 0, stream>>>(
        Wconv_b, 512, 0, k1t, 512, 262144, k1c, 512, 262144, 512, bconv, nullptr, 0);

    // fused scores + mask + softmax + attn write + PV -> out1 bf16
    scores_pv_k<<<1024, 512, 0, stream>>>(
        q1c, k1c, v1t, attn, out1, mask1, mask2, scale);

    // FC + f32 residual
    gemm_bt<4><<<dim3(6, 128, 1), 256, 0, stream>>>(
        out1, 1024, 0, WfcT, 1024, 0, out2, 768, 0, 1024, nullptr, q, 768);

    // LayerNorm + nan->0 -> f32 d_out
    ln_k<<<4096, 256, 0, stream>>>(out2, gamma, beta, out);
}